// Round 1
// baseline (1134.138 us; speedup 1.0000x reference)
//
#include <hip/hip_runtime.h>
#include <cstdint>
#include <cstddef>

#define NN 16
#define DD 2048
#define BB 4096

#define TM 256
#define TN 128
#define BK 64
// One K-tile buffer: A = TM*BK + B = TN*BK halves = 24576 halves = 48 KB.
// Triple-buffered: 3 x 48 KB = 144 KB LDS (1 block/CU).
#define BUFH (TM * BK + TN * BK)

typedef _Float16 half8 __attribute__((ext_vector_type(8)));
typedef _Float16 half4 __attribute__((ext_vector_type(4)));
typedef float f32x4 __attribute__((ext_vector_type(4)));

__device__ __forceinline__ float fast_tanh(float x) {
  float ax = __builtin_fabsf(x);
  float e = __expf(-2.0f * ax);
  float t = (1.0f - e) / (1.0f + e);
  return x < 0.0f ? -t : t;
}

// W fp32 [i][k][n]  ->  Wh fp16 [i][n][k]   (transpose + downconvert)
__global__ __launch_bounds__(256) void wconv_kernel(const float* __restrict__ W,
                                                    _Float16* __restrict__ Wh) {
  __shared__ _Float16 tile[64][80];
  const int i = blockIdx.z;
  const int k0 = blockIdx.y * 64;
  const int n0 = blockIdx.x * 64;
  const float* Wi = W + (size_t)i * DD * DD;
  _Float16* Whi = Wh + (size_t)i * DD * DD;
  const int t = threadIdx.x;
  const int cr = t >> 4;
  const int cc = (t & 15) * 4;
#pragma unroll
  for (int p = 0; p < 4; ++p) {
    int r = p * 16 + cr;
    float4 v = *(const float4*)(Wi + (size_t)(k0 + r) * DD + n0 + cc);
    tile[cc + 0][r] = (_Float16)v.x;
    tile[cc + 1][r] = (_Float16)v.y;
    tile[cc + 2][r] = (_Float16)v.z;
    tile[cc + 3][r] = (_Float16)v.w;
  }
  __syncthreads();
  const int wr = t >> 3;
  const int wc = (t & 7) * 8;
#pragma unroll
  for (int p = 0; p < 2; ++p) {
    int n = p * 32 + wr;
    half8 v = *(const half8*)&tile[n][wc];
    *(half8*)(Whi + (size_t)(n0 + n) * DD + k0 + wc) = v;
  }
}

// x fp32 -> S0 fp16 (elementwise)
__global__ __launch_bounds__(256) void xconv_kernel(const float* __restrict__ x,
                                                    _Float16* __restrict__ s0) {
  size_t idx = (size_t)(blockIdx.x * 256 + threadIdx.x) * 4;
  float4 v = *(const float4*)(x + idx);
  half4 o;
  o.x = (_Float16)v.x; o.y = (_Float16)v.y; o.z = (_Float16)v.z; o.w = (_Float16)v.w;
  *(half4*)(s0 + idx) = o;
}

// One DAG node: out = tanh(S @ Wt^T + bias).
// 256x128 tile, 512 threads (8 waves 4Mx2N, each 64x64), BK=64.
// Triple-buffered LDS with counted s_waitcnt vmcnt(6): while computing tile t,
// tile t+1 is fully landed, tile t+2 is in flight. One raw s_barrier per
// K-tile; vmcnt never drains to 0 in the main loop (T3+T4). setprio around
// MFMA clusters (T5). XOR k-chunk swizzle; XCD-aware block mapping.
// 256 blocks @ 1 block/CU (144 KB LDS) = exact full residency.
__global__ __launch_bounds__(512, 2) void node_gemm(
    const _Float16* __restrict__ S,      // [BB][DD] fp16 pre-summed input
    const _Float16* __restrict__ Wt,     // [DD][DD] fp16, layout [n][k]
    const float* __restrict__ bias,      // [DD]
    _Float16* __restrict__ Y,            // [BB][DD] fp16 tanh output
    const _Float16* __restrict__ Yprev,  // may be null (node 0)
    _Float16* __restrict__ Snext,        // [BB][DD] fp16 next-node input
    float* __restrict__ Ofinal)          // non-null only for terminal node
{
  __shared__ _Float16 smem[3 * BUFH];  // 144 KB

  const int t = threadIdx.x;
  const int lane = t & 63;
  const int wave = t >> 6;
  const int bid = blockIdx.x;
  // XCD-aware: XCD (bid&7) owns 32 consecutive swz = 2 n-tiles x 16 m-tiles.
  // Its 2 B-panels (2 x 512 KB) stay L2-resident, shared by 16 blocks each.
  const int swz = (bid & 7) * 32 + (bid >> 3);
  const int n0 = (swz >> 4) * TN;  // 16 n-tiles
  const int m0 = (swz & 15) * TM;  // 16 m-tiles
  const int wm = (wave >> 1) * 64;  // wave tile: 64m x 64n
  const int wn = (wave & 1) * 64;
  const int lrow = lane & 15;
  const int lq = lane >> 4;

  f32x4 acc[4][4];
#pragma unroll
  for (int i = 0; i < 4; ++i)
#pragma unroll
    for (int j = 0; j < 4; ++j) acc[i][j] = (f32x4)0.0f;

  // Staging: thread t covers chunk c = t&7 (16B) of row (t>>3) in each 64-row
  // block. XOR swizzle: LDS[row][c*8..] holds global k-chunk (c ^ (row&7));
  // row&7 invariant under +64-row steps.
  const int srow = t >> 3;
  const int ska = ((t & 7) ^ (srow & 7)) * 8;
  const _Float16* ag = S + (size_t)(m0 + srow) * DD + ska;
  const _Float16* bg = Wt + (size_t)(n0 + srow) * DD + ska;

  // 6 global_load_lds per wave per K-tile (4 for A 256x64, 2 for B 128x64).
  auto stage = [&](int buf, int k0) {
    const _Float16* a = ag + k0;
    const _Float16* b = bg + k0;
    _Float16* al = smem + buf * BUFH + t * 8;
    _Float16* bl = smem + buf * BUFH + TM * BK + t * 8;
#pragma unroll
    for (int r = 0; r < 4; ++r)
      __builtin_amdgcn_global_load_lds(
          (const __attribute__((address_space(1))) void*)(a + (size_t)(r * 64) * DD),
          (__attribute__((address_space(3))) void*)(al + r * 4096), 16, 0, 0);
#pragma unroll
    for (int r = 0; r < 2; ++r)
      __builtin_amdgcn_global_load_lds(
          (const __attribute__((address_space(1))) void*)(b + (size_t)(r * 64) * DD),
          (__attribute__((address_space(3))) void*)(bl + r * 4096), 16, 0, 0);
  };

  // Prologue: tiles 0 and 1 in flight; wait tile 0 (6 newest stay outstanding).
  stage(0, 0);
  stage(1, BK);
  asm volatile("s_waitcnt vmcnt(6)" ::: "memory");
  asm volatile("s_barrier" ::: "memory");

  int cur = 0, nxt = 2;
  for (int i = 0; i < DD / BK; ++i) {
    // Issue tile i+2 into the buffer last read at tile i-1 (all waves passed
    // the end-of-(i-1) barrier, so no WAR race).
    if (i <= DD / BK - 3) stage(nxt, (i + 2) * BK);
    const _Float16* Ap = smem + cur * BUFH;
    const _Float16* Bp = smem + cur * BUFH + TM * BK;
#pragma unroll
    for (int ks = 0; ks < BK; ks += 32) {
      const int cx = (((ks >> 3) + lq) ^ (lrow & 7)) * 8;
      half8 a[4], b[4];
#pragma unroll
      for (int mt = 0; mt < 4; ++mt)
        a[mt] = *(const half8*)(Ap + (wm + mt * 16 + lrow) * BK + cx);
#pragma unroll
      for (int nt = 0; nt < 4; ++nt)
        b[nt] = *(const half8*)(Bp + (wn + nt * 16 + lrow) * BK + cx);
      __builtin_amdgcn_s_setprio(1);
#pragma unroll
      for (int mt = 0; mt < 4; ++mt)
#pragma unroll
        for (int nt = 0; nt < 4; ++nt)
          acc[mt][nt] =
              __builtin_amdgcn_mfma_f32_16x16x32_f16(a[mt], b[nt], acc[mt][nt], 0, 0, 0);
      __builtin_amdgcn_s_setprio(0);
    }
    // Publish tile i+1: its 6 loads are the oldest outstanding; the 6 newest
    // (tile i+2) stay in flight across the barrier.
    if (i < DD / BK - 2) {
      asm volatile("s_waitcnt vmcnt(6)" ::: "memory");
      asm volatile("s_barrier" ::: "memory");
    } else if (i == DD / BK - 2) {
      asm volatile("s_waitcnt vmcnt(0)" ::: "memory");
      asm volatile("s_barrier" ::: "memory");
    }
    cur = (cur == 2) ? 0 : cur + 1;
    nxt = (nxt == 2) ? 0 : nxt + 1;
  }

  // Epilogue: acc -> LDS (fp16, [256][128]) -> coalesced global stores.
  __syncthreads();
  _Float16* CT = smem;  // 32768 halves = 64 KB, reuse staging region
  float bv[4];
#pragma unroll
  for (int nt = 0; nt < 4; ++nt) bv[nt] = bias[n0 + wn + nt * 16 + lrow];
#pragma unroll
  for (int mt = 0; mt < 4; ++mt)
#pragma unroll
    for (int nt = 0; nt < 4; ++nt)
#pragma unroll
      for (int r = 0; r < 4; ++r) {
        int row = wm + mt * 16 + lq * 4 + r;
        int col = wn + nt * 16 + lrow;
        CT[row * TN + col] = (_Float16)fast_tanh(acc[mt][nt][r] + bv[nt]);
      }
  __syncthreads();

#pragma unroll
  for (int pp = 0; pp < 8; ++pp) {
    int idx = pp * 4096 + t * 8;
    int row = idx >> 7;
    int col = idx & 127;
    size_t off = (size_t)(m0 + row) * DD + n0 + col;
    half8 y = *(const half8*)&CT[idx];
    if (Ofinal) {
      float4 f0 = {(float)y[0], (float)y[1], (float)y[2], (float)y[3]};
      float4 f1 = {(float)y[4], (float)y[5], (float)y[6], (float)y[7]};
      *(float4*)(Ofinal + off) = f0;
      *(float4*)(Ofinal + off + 4) = f1;
    } else {
      *(half8*)(Y + off) = y;
      half8 s = y;
      if (Yprev) s = s + *(const half8*)(Yprev + off);
      *(half8*)(Snext + off) = s;
    }
  }
}

extern "C" void kernel_launch(void* const* d_in, const int* in_sizes, int n_in,
                              void* d_out, int out_size, void* d_ws, size_t ws_size,
                              hipStream_t stream) {
  const float* x = (const float*)d_in[0];
  const float* W = (const float*)d_in[1];
  const float* b = (const float*)d_in[2];
  float* out = (float*)d_out;
  char* ws = (char*)d_ws;

  _Float16* Wh = (_Float16*)ws;  // 128 MB
  size_t wbytes = (size_t)NN * DD * DD * sizeof(_Float16);
  _Float16* S0 = (_Float16*)(ws + wbytes);
  _Float16* S1 = S0 + (size_t)BB * DD;
  _Float16* Y0 = S1 + (size_t)BB * DD;
  _Float16* Y1 = Y0 + (size_t)BB * DD;

  wconv_kernel<<<dim3(DD / 64, DD / 64, NN), dim3(256), 0, stream>>>(W, Wh);
  xconv_kernel<<<dim3((BB * DD) / 1024), dim3(256), 0, stream>>>(x, S0);

  _Float16* Sb[2] = {S0, S1};
  _Float16* Yb[2] = {Y0, Y1};
  dim3 ggrid((BB / TM) * (DD / TN));  // 16 x 16 = 256 blocks = 1/CU exact
  for (int i = 0; i < NN; ++i) {
    const _Float16* Sin = Sb[i & 1];
    _Float16* Sout = Sb[(i + 1) & 1];
    _Float16* Yout = Yb[i & 1];
    const _Float16* Yp = (i >= 1) ? Yb[(i + 1) & 1] : nullptr;
    const bool last = (i == NN - 1);
    node_gemm<<<ggrid, dim3(512), 0, stream>>>(Sin, Wh + (size_t)i * DD * DD,
                                               b + (size_t)i * DD, Yout, Yp, Sout,
                                               last ? out : nullptr);
  }
  (void)in_sizes; (void)n_in; (void)out_size; (void)ws_size;
}

// Round 2
// 1112.811 us; speedup vs baseline: 1.0192x; 1.0192x over previous
//
#include <hip/hip_runtime.h>
#include <cstdint>
#include <cstddef>

#define NN 16
#define DD 2048
#define BB 4096

#define TM 256
#define TN 128
#define BK 64
// One K-tile buffer: A = TM*BK + B = TN*BK halves = 24576 halves = 48 KB.
// Triple-buffered: 3 x 48 KB = 144 KB LDS (1 block/CU).
#define BUFH (TM * BK + TN * BK)

typedef _Float16 half8 __attribute__((ext_vector_type(8)));
typedef _Float16 half4 __attribute__((ext_vector_type(4)));
typedef float f32x4 __attribute__((ext_vector_type(4)));

__device__ __forceinline__ float fast_tanh(float x) {
  float ax = __builtin_fabsf(x);
  float e = __expf(-2.0f * ax);
  float t = (1.0f - e) / (1.0f + e);
  return x < 0.0f ? -t : t;
}

// W fp32 [i][k][n]  ->  Wh fp16 [i][n][k]   (transpose + downconvert)
__global__ __launch_bounds__(256) void wconv_kernel(const float* __restrict__ W,
                                                    _Float16* __restrict__ Wh) {
  __shared__ _Float16 tile[64][80];
  const int i = blockIdx.z;
  const int k0 = blockIdx.y * 64;
  const int n0 = blockIdx.x * 64;
  const float* Wi = W + (size_t)i * DD * DD;
  _Float16* Whi = Wh + (size_t)i * DD * DD;
  const int t = threadIdx.x;
  const int cr = t >> 4;
  const int cc = (t & 15) * 4;
#pragma unroll
  for (int p = 0; p < 4; ++p) {
    int r = p * 16 + cr;
    float4 v = *(const float4*)(Wi + (size_t)(k0 + r) * DD + n0 + cc);
    tile[cc + 0][r] = (_Float16)v.x;
    tile[cc + 1][r] = (_Float16)v.y;
    tile[cc + 2][r] = (_Float16)v.z;
    tile[cc + 3][r] = (_Float16)v.w;
  }
  __syncthreads();
  const int wr = t >> 3;
  const int wc = (t & 7) * 8;
#pragma unroll
  for (int p = 0; p < 2; ++p) {
    int n = p * 32 + wr;
    half8 v = *(const half8*)&tile[n][wc];
    *(half8*)(Whi + (size_t)(n0 + n) * DD + k0 + wc) = v;
  }
}

// x fp32 -> S0 fp16 (elementwise)
__global__ __launch_bounds__(256) void xconv_kernel(const float* __restrict__ x,
                                                    _Float16* __restrict__ s0) {
  size_t idx = (size_t)(blockIdx.x * 256 + threadIdx.x) * 4;
  float4 v = *(const float4*)(x + idx);
  half4 o;
  o.x = (_Float16)v.x; o.y = (_Float16)v.y; o.z = (_Float16)v.z; o.w = (_Float16)v.w;
  *(half4*)(s0 + idx) = o;
}

// One DAG node: out = tanh(S @ Wt^T + bias).
// 256x128 tile, 512 threads (8 waves 4Mx2N, each 64x64), BK=64.
// Triple-buffered LDS; each K-tile split into 4 phases (kstep x N-half):
//   {ds_read fragment subtile || 2 global_load_lds stage issues
//    -> s_barrier -> setprio(1) -> 8 MFMA -> setprio(0)}
// Phase 3 carries the publish s_waitcnt vmcnt(6) + s_barrier (per-wave vmcnt
// made globally valid by the barrier). vmcnt never drains to 0 in the main
// loop (T3+T4 fine interleave). XOR k-chunk swizzle; XCD 4m x 8n mapping.
// 256 blocks @ 1 block/CU (144 KB LDS) = exact full residency.
__global__ __launch_bounds__(512, 2) void node_gemm(
    const _Float16* __restrict__ S,      // [BB][DD] fp16 pre-summed input
    const _Float16* __restrict__ Wt,     // [DD][DD] fp16, layout [n][k]
    const float* __restrict__ bias,      // [DD]
    _Float16* __restrict__ Y,            // [BB][DD] fp16 tanh output
    const _Float16* __restrict__ Yprev,  // may be null (node 0)
    _Float16* __restrict__ Snext,        // [BB][DD] fp16 next-node input
    float* __restrict__ Ofinal)          // non-null only for terminal node
{
  __shared__ _Float16 smem[3 * BUFH];  // 144 KB

  const int t = threadIdx.x;
  const int lane = t & 63;
  const int wave = t >> 6;
  const int bid = blockIdx.x;
  // XCD-aware: XCD (bid&7) owns a 4m x 8n tile block (A 4MB + B 4MB footprint;
  // per-K-tile working set ~256KB -> L2-resident). Bijective: bid bits
  // b0b1|b3b4 -> m-tile, b2|b5b6b7 -> n-tile.
  const int xcd = bid & 7;
  const int loc = bid >> 3;
  const int m0 = ((xcd & 3) * 4 + (loc & 3)) * TM;   // 16 m-tiles
  const int n0 = ((xcd >> 2) * 8 + (loc >> 2)) * TN; // 16 n-tiles
  const int wm = (wave >> 1) * 64;  // wave tile: 64m x 64n
  const int wn = (wave & 1) * 64;
  const int lrow = lane & 15;
  const int lq = lane >> 4;

  f32x4 acc[4][4];
#pragma unroll
  for (int i = 0; i < 4; ++i)
#pragma unroll
    for (int j = 0; j < 4; ++j) acc[i][j] = (f32x4)0.0f;

  // Staging: thread t covers chunk c = t&7 (16B) of row (t>>3) in each 64-row
  // block. XOR swizzle: LDS[row][c*8..] holds global k-chunk (c ^ (row&7));
  // row&7 invariant under +64-row steps.
  const int srow = t >> 3;
  const int ska = ((t & 7) ^ (srow & 7)) * 8;
  const _Float16* ag = S + (size_t)(m0 + srow) * DD + ska;
  const _Float16* bg = Wt + (size_t)(n0 + srow) * DD + ska;

  // 6 global_load_lds per wave per K-tile (4 for A 256x64, 2 for B 128x64),
  // issued 2 per phase across phases 0-2.
  auto stageA2 = [&](int buf, int k0, int r0) {
    const _Float16* a = ag + k0;
    _Float16* al = smem + buf * BUFH + t * 8;
#pragma unroll
    for (int r = 0; r < 2; ++r)
      __builtin_amdgcn_global_load_lds(
          (const __attribute__((address_space(1))) void*)(a + (size_t)((r0 + r) * 64) * DD),
          (__attribute__((address_space(3))) void*)(al + (r0 + r) * 4096), 16, 0, 0);
  };
  auto stageB2 = [&](int buf, int k0) {
    const _Float16* b = bg + k0;
    _Float16* bl = smem + buf * BUFH + TM * BK + t * 8;
#pragma unroll
    for (int r = 0; r < 2; ++r)
      __builtin_amdgcn_global_load_lds(
          (const __attribute__((address_space(1))) void*)(b + (size_t)(r * 64) * DD),
          (__attribute__((address_space(3))) void*)(bl + r * 4096), 16, 0, 0);
  };

  // Prologue: tiles 0 and 1 in flight; wait tile 0 (6 newest stay outstanding).
  stageA2(0, 0, 0); stageA2(0, 0, 2); stageB2(0, 0);
  stageA2(1, BK, 0); stageA2(1, BK, 2); stageB2(1, BK);
  asm volatile("s_waitcnt vmcnt(6)" ::: "memory");
  asm volatile("s_barrier" ::: "memory");

  int cur = 0, nxt = 2;
  for (int i = 0; i < DD / BK; ++i) {
    const _Float16* Ap = smem + cur * BUFH;
    const _Float16* Bp = smem + cur * BUFH + TM * BK;
    const bool pf = (i <= DD / BK - 3);
    const int pk = (i + 2) * BK;
    const int cx0 = ((0 + lq) ^ (lrow & 7)) * 8;  // k-step 0 swizzled chunk
    const int cx1 = ((4 + lq) ^ (lrow & 7)) * 8;  // k-step 1
    half8 a[4], b[4];

    // ---- phase 0: k-step 0, N-low ----
#pragma unroll
    for (int mt = 0; mt < 4; ++mt)
      a[mt] = *(const half8*)(Ap + (wm + mt * 16 + lrow) * BK + cx0);
    b[0] = *(const half8*)(Bp + (wn + 0 + lrow) * BK + cx0);
    b[1] = *(const half8*)(Bp + (wn + 16 + lrow) * BK + cx0);
    if (pf) stageA2(nxt, pk, 0);
    asm volatile("s_barrier" ::: "memory");
    __builtin_amdgcn_s_setprio(1);
#pragma unroll
    for (int mt = 0; mt < 4; ++mt) {
      acc[mt][0] = __builtin_amdgcn_mfma_f32_16x16x32_f16(a[mt], b[0], acc[mt][0], 0, 0, 0);
      acc[mt][1] = __builtin_amdgcn_mfma_f32_16x16x32_f16(a[mt], b[1], acc[mt][1], 0, 0, 0);
    }
    __builtin_amdgcn_s_setprio(0);

    // ---- phase 1: k-step 0, N-high (A frags reused) ----
    b[2] = *(const half8*)(Bp + (wn + 32 + lrow) * BK + cx0);
    b[3] = *(const half8*)(Bp + (wn + 48 + lrow) * BK + cx0);
    if (pf) stageA2(nxt, pk, 2);
    asm volatile("s_barrier" ::: "memory");
    __builtin_amdgcn_s_setprio(1);
#pragma unroll
    for (int mt = 0; mt < 4; ++mt) {
      acc[mt][2] = __builtin_amdgcn_mfma_f32_16x16x32_f16(a[mt], b[2], acc[mt][2], 0, 0, 0);
      acc[mt][3] = __builtin_amdgcn_mfma_f32_16x16x32_f16(a[mt], b[3], acc[mt][3], 0, 0, 0);
    }
    __builtin_amdgcn_s_setprio(0);

    // ---- phase 2: k-step 1, N-low ----
#pragma unroll
    for (int mt = 0; mt < 4; ++mt)
      a[mt] = *(const half8*)(Ap + (wm + mt * 16 + lrow) * BK + cx1);
    b[0] = *(const half8*)(Bp + (wn + 0 + lrow) * BK + cx1);
    b[1] = *(const half8*)(Bp + (wn + 16 + lrow) * BK + cx1);
    if (pf) stageB2(nxt, pk);
    asm volatile("s_barrier" ::: "memory");
    __builtin_amdgcn_s_setprio(1);
#pragma unroll
    for (int mt = 0; mt < 4; ++mt) {
      acc[mt][0] = __builtin_amdgcn_mfma_f32_16x16x32_f16(a[mt], b[0], acc[mt][0], 0, 0, 0);
      acc[mt][1] = __builtin_amdgcn_mfma_f32_16x16x32_f16(a[mt], b[1], acc[mt][1], 0, 0, 0);
    }
    __builtin_amdgcn_s_setprio(0);

    // ---- phase 3: k-step 1, N-high + publish next tile ----
    b[2] = *(const half8*)(Bp + (wn + 32 + lrow) * BK + cx1);
    b[3] = *(const half8*)(Bp + (wn + 48 + lrow) * BK + cx1);
    // Publish tile i+1: its 6 loads are the oldest outstanding; the 6 newest
    // (tile i+2, issued this iteration) stay in flight across the barrier.
    if (i < DD / BK - 2) {
      asm volatile("s_waitcnt vmcnt(6)" ::: "memory");
    } else if (i == DD / BK - 2) {
      asm volatile("s_waitcnt vmcnt(0)" ::: "memory");
    }
    asm volatile("s_barrier" ::: "memory");
    __builtin_amdgcn_s_setprio(1);
#pragma unroll
    for (int mt = 0; mt < 4; ++mt) {
      acc[mt][2] = __builtin_amdgcn_mfma_f32_16x16x32_f16(a[mt], b[2], acc[mt][2], 0, 0, 0);
      acc[mt][3] = __builtin_amdgcn_mfma_f32_16x16x32_f16(a[mt], b[3], acc[mt][3], 0, 0, 0);
    }
    __builtin_amdgcn_s_setprio(0);

    cur = (cur == 2) ? 0 : cur + 1;
    nxt = (nxt == 2) ? 0 : nxt + 1;
  }

  // Epilogue: acc -> LDS (fp16, [256][128]) -> coalesced global stores.
  __syncthreads();
  _Float16* CT = smem;  // 32768 halves = 64 KB, reuse staging region
  float bv[4];
#pragma unroll
  for (int nt = 0; nt < 4; ++nt) bv[nt] = bias[n0 + wn + nt * 16 + lrow];
#pragma unroll
  for (int mt = 0; mt < 4; ++mt)
#pragma unroll
    for (int nt = 0; nt < 4; ++nt)
#pragma unroll
      for (int r = 0; r < 4; ++r) {
        int row = wm + mt * 16 + lq * 4 + r;
        int col = wn + nt * 16 + lrow;
        CT[row * TN + col] = (_Float16)fast_tanh(acc[mt][nt][r] + bv[nt]);
      }
  __syncthreads();

#pragma unroll
  for (int pp = 0; pp < 8; ++pp) {
    int idx = pp * 4096 + t * 8;
    int row = idx >> 7;
    int col = idx & 127;
    size_t off = (size_t)(m0 + row) * DD + n0 + col;
    half8 y = *(const half8*)&CT[idx];
    if (Ofinal) {
      float4 f0 = {(float)y[0], (float)y[1], (float)y[2], (float)y[3]};
      float4 f1 = {(float)y[4], (float)y[5], (float)y[6], (float)y[7]};
      *(float4*)(Ofinal + off) = f0;
      *(float4*)(Ofinal + off + 4) = f1;
    } else {
      *(half8*)(Y + off) = y;
      half8 s = y;
      if (Yprev) s = s + *(const half8*)(Yprev + off);
      *(half8*)(Snext + off) = s;
    }
  }
}

extern "C" void kernel_launch(void* const* d_in, const int* in_sizes, int n_in,
                              void* d_out, int out_size, void* d_ws, size_t ws_size,
                              hipStream_t stream) {
  const float* x = (const float*)d_in[0];
  const float* W = (const float*)d_in[1];
  const float* b = (const float*)d_in[2];
  float* out = (float*)d_out;
  char* ws = (char*)d_ws;

  _Float16* Wh = (_Float16*)ws;  // 128 MB
  size_t wbytes = (size_t)NN * DD * DD * sizeof(_Float16);
  _Float16* S0 = (_Float16*)(ws + wbytes);
  _Float16* S1 = S0 + (size_t)BB * DD;
  _Float16* Y0 = S1 + (size_t)BB * DD;
  _Float16* Y1 = Y0 + (size_t)BB * DD;

  wconv_kernel<<<dim3(DD / 64, DD / 64, NN), dim3(256), 0, stream>>>(W, Wh);
  xconv_kernel<<<dim3((BB * DD) / 1024), dim3(256), 0, stream>>>(x, S0);

  _Float16* Sb[2] = {S0, S1};
  _Float16* Yb[2] = {Y0, Y1};
  dim3 ggrid((BB / TM) * (DD / TN));  // 16 x 16 = 256 blocks = 1/CU exact
  for (int i = 0; i < NN; ++i) {
    const _Float16* Sin = Sb[i & 1];
    _Float16* Sout = Sb[(i + 1) & 1];
    _Float16* Yout = Yb[i & 1];
    const _Float16* Yp = (i >= 1) ? Yb[(i + 1) & 1] : nullptr;
    const bool last = (i == NN - 1);
    node_gemm<<<ggrid, dim3(512), 0, stream>>>(Sin, Wh + (size_t)i * DD * DD,
                                               b + (size_t)i * DD, Yout, Yp, Sout,
                                               last ? out : nullptr);
  }
  (void)in_sizes; (void)n_in; (void)out_size; (void)ws_size;
}